// Round 13
// baseline (219.428 us; speedup 1.0000x reference)
//
#include <hip/hip_runtime.h>
#include <stdint.h>

#define B_ 8
#define N_ 4096
#define C_ 512
#define H_ 256
#define NC_ 1000

typedef float v4f __attribute__((ext_vector_type(4)));
typedef short v8s __attribute__((ext_vector_type(8)));
typedef unsigned short ushort_t;

__device__ __forceinline__ uint32_t f2bf1(float f) {
    uint32_t u = __float_as_uint(f);
    return (u + 0x7FFFu + ((u >> 16) & 1u)) >> 16;
}
__device__ __forceinline__ uint32_t pk2(float lo, float hi) {
#if __has_builtin(__builtin_amdgcn_cvt_pk_bf16_f32)
    auto r = __builtin_amdgcn_cvt_pk_bf16_f32(lo, hi);   // v_cvt_pk_bf16_f32
    return __builtin_bit_cast(uint32_t, r);
#else
    return f2bf1(lo) | (f2bf1(hi) << 16);
#endif
}

// ---- prep: proj_W -> bf16 B-fragment order only (gather is dead code: the
// permutation feeds a permutation-invariant token mean). --------------------
// Wfrag (uint4 units): slot[(ntile*16 + kb)*64 + q*16 + c] holds
// bf16(W[ntile*16+c][kb*32 + q*8 + j]), j=0..7.  (exact 524288 B)
__global__ void prep_kernel(const float* __restrict__ W, ushort_t* __restrict__ Wfrag) {
    int i = blockIdx.x * 256 + threadIdx.x;            // 0..32767 = d*64 + kb*4 + q
    int d = i >> 6, kb = (i >> 2) & 15, q = i & 3;
    const float4* src = (const float4*)(W + d * C_ + kb * 32 + q * 8);
    float4 v0 = src[0], v1 = src[1];
    uint4 pk;
    pk.x = pk2(v0.x, v0.y); pk.y = pk2(v0.z, v0.w);
    pk.z = pk2(v1.x, v1.y); pk.w = pk2(v1.z, v1.w);
    ((uint4*)Wfrag)[((d >> 4) * 16 + kb) * 64 + q * 16 + (d & 15)] = pk;
}

// ---- fused GEMM+bias+LN+col-pool + prev-pool, 512 blocks = EXACTLY 2/CU ----
// R12 structure (tail removed: 45us, total 214.7 best). R13 change: prev
// loads in FOUR 4-deep batches (16 VGPR live, was 8-deep/32) interleaved
// with epilogue sub-phases — flattens the register-pressure peak that R12's
// WRITE_SIZE (6.1MB, ~4.7MB scratch spill) exposed. Spill sentinel:
// WRITE_SIZE should return to ~1.6MB.
__global__ __launch_bounds__(512, 4)
void gemm_ln_pool(const float* __restrict__ feat, const float* __restrict__ prev,
                  const ushort_t* __restrict__ Wfrag,
                  const float* __restrict__ pb, const float* __restrict__ lg,
                  const float* __restrict__ lb,
                  float* __restrict__ partialG) {    // [512][512]
    __shared__ v8s Abuf[4096];          // 64KB A-tile; reused as prev scratch
    __shared__ float RowS[64], RowQ[64], ColS[512];

    const int gix = blockIdx.x;                         // 0..511
    const int t = threadIdx.x;
    const int b = gix >> 6;
    const int row0 = (gix & 63) << 6;
    const int wv = t >> 6, lane = t & 63, c = lane & 15, q = lane >> 4;

    if (t < 64) { RowS[t] = 0.f; RowQ[t] = 0.f; }

    // ---- phase 1: stage A tile (sequential rows, fp32->bf16), nt loads ----
    const int arow = t >> 3;                           // 0..63
    const int acol8 = t & 7;
    const v4f* asrc = (const v4f*)(feat + ((size_t)(b * N_ + row0 + arow) * C_));
#pragma unroll 4
    for (int s = 0; s < 8; s++) {
        const int chunk = s * 8 + acol8;               // logical 16B-chunk 0..63
        v4f f0 = __builtin_nontemporal_load(asrc + chunk * 2);
        v4f f1 = __builtin_nontemporal_load(asrc + chunk * 2 + 1);
        uint4 pk;
        pk.x = pk2(f0.x, f0.y); pk.y = pk2(f0.z, f0.w);
        pk.z = pk2(f1.x, f1.y); pk.w = pk2(f1.z, f1.w);
        ((uint4*)Abuf)[arow * 64 + (chunk ^ (arow & 7))] = pk;
    }

    // B fragment bases: wave wv owns cols [64*wv, 64*wv+64), ntile = wv*4+nt
    const ushort_t* fb[4];
#pragma unroll
    for (int nt = 0; nt < 4; nt++)
        fb[nt] = Wfrag + (wv * 4 + nt) * 8192 + lane * 8;

    v4f acc[4][4];
    const v4f vzero = {0.f, 0.f, 0.f, 0.f};
#pragma unroll
    for (int mt = 0; mt < 4; mt++)
#pragma unroll
        for (int nt = 0; nt < 4; nt++) acc[mt][nt] = vzero;

    __syncthreads();

    // ---- phase 2: barrier-free K loop, only L2/L3-hit B loads in vm queue
#pragma unroll 2
    for (int kb = 0; kb < 16; kb++) {
        v8s af[4], bf[4];
#pragma unroll
        for (int nt = 0; nt < 4; nt++)
            bf[nt] = *((const v8s*)(fb[nt] + kb * 512));
#pragma unroll
        for (int mt = 0; mt < 4; mt++)
            af[mt] = Abuf[(mt * 16 + c) * 64 + ((kb * 4 + q) ^ (c & 7))];
#pragma unroll
        for (int mt = 0; mt < 4; mt++)
#pragma unroll
            for (int nt = 0; nt < 4; nt++)
                acc[mt][nt] = __builtin_amdgcn_mfma_f32_16x16x32_bf16(
                    af[mt], bf[nt], acc[mt][nt], 0, 0, 0);
    }

    // prev stream setup: thread t owns float4-col (t&127), rowgroup (t>>7)
    const int col4 = t & 127, rg = t >> 7;
    const v4f* psrc =
        (const v4f*)(prev + (size_t)(b * N_ + row0 + rg * 16) * C_) + col4;
    v4f pv[4], ps = {0.f, 0.f, 0.f, 0.f};
    // batch 0 issued right after K-loop; hidden under stats(mt=0,1)
#pragma unroll
    for (int r = 0; r < 4; r++)
        pv[r] = __builtin_nontemporal_load(psrc + r * 128);

    // ---- epilogue pass 1: bias + LN row stats, split in halves ----
    float pb4[4], lg4[4], lb4[4];
#pragma unroll
    for (int nt = 0; nt < 4; nt++) {
        int n = wv * 64 + nt * 16 + c;
        pb4[nt] = pb[n]; lg4[nt] = lg[n]; lb4[nt] = lb[n];
    }
#pragma unroll
    for (int mt = 0; mt < 2; mt++) {                   // stats half A (mt 0,1)
#pragma unroll
        for (int reg = 0; reg < 4; reg++) {
            float s1 = 0.f, s2 = 0.f;
#pragma unroll
            for (int nt = 0; nt < 4; nt++) {
                float v = acc[mt][nt][reg] + pb4[nt];
                acc[mt][nt][reg] = v;
                s1 += v; s2 += v * v;
            }
#pragma unroll
            for (int d = 1; d < 16; d <<= 1) {
                s1 += __shfl_xor(s1, d);
                s2 += __shfl_xor(s2, d);
            }
            if (c == 0) {
                int r = mt * 16 + q * 4 + reg;
                atomicAdd(&RowS[r], s1);
                atomicAdd(&RowQ[r], s2);
            }
        }
    }
    // consume batch 0, issue batch 1 (hidden under stats half B)
    ps += (pv[0] + pv[1]) + (pv[2] + pv[3]);
#pragma unroll
    for (int r = 0; r < 4; r++)
        pv[r] = __builtin_nontemporal_load(psrc + (4 + r) * 128);
#pragma unroll
    for (int mt = 2; mt < 4; mt++) {                   // stats half B (mt 2,3)
#pragma unroll
        for (int reg = 0; reg < 4; reg++) {
            float s1 = 0.f, s2 = 0.f;
#pragma unroll
            for (int nt = 0; nt < 4; nt++) {
                float v = acc[mt][nt][reg] + pb4[nt];
                acc[mt][nt][reg] = v;
                s1 += v; s2 += v * v;
            }
#pragma unroll
            for (int d = 1; d < 16; d <<= 1) {
                s1 += __shfl_xor(s1, d);
                s2 += __shfl_xor(s2, d);
            }
            if (c == 0) {
                int r = mt * 16 + q * 4 + reg;
                atomicAdd(&RowS[r], s1);
                atomicAdd(&RowQ[r], s2);
            }
        }
    }
    __syncthreads();
    if (t < 64) {
        float mu = RowS[t] * (1.f / C_);
        float var = RowQ[t] * (1.f / C_) - mu * mu;
        RowS[t] = mu;
        RowQ[t] = rsqrtf(var + 1e-5f);
    }
    // consume batch 1, issue batch 2 (hidden under barrier + normalize half A)
    ps += (pv[0] + pv[1]) + (pv[2] + pv[3]);
#pragma unroll
    for (int r = 0; r < 4; r++)
        pv[r] = __builtin_nontemporal_load(psrc + (8 + r) * 128);
    __syncthreads();

    // ---- epilogue pass 2: normalize + column pool, split in halves ----
    float col[4] = {0.f, 0.f, 0.f, 0.f};
#pragma unroll
    for (int mt = 0; mt < 2; mt++) {                   // normalize half A
#pragma unroll
        for (int reg = 0; reg < 4; reg++) {
            int r = mt * 16 + q * 4 + reg;
            float mu = RowS[r], rs = RowQ[r];
#pragma unroll
            for (int nt = 0; nt < 4; nt++)
                col[nt] += (acc[mt][nt][reg] - mu) * rs * lg4[nt] + lb4[nt];
        }
    }
    // consume batch 2, issue batch 3 (hidden under normalize half B)
    ps += (pv[0] + pv[1]) + (pv[2] + pv[3]);
#pragma unroll
    for (int r = 0; r < 4; r++)
        pv[r] = __builtin_nontemporal_load(psrc + (12 + r) * 128);
#pragma unroll
    for (int mt = 2; mt < 4; mt++) {                   // normalize half B
#pragma unroll
        for (int reg = 0; reg < 4; reg++) {
            int r = mt * 16 + q * 4 + reg;
            float mu = RowS[r], rs = RowQ[r];
#pragma unroll
            for (int nt = 0; nt < 4; nt++)
                col[nt] += (acc[mt][nt][reg] - mu) * rs * lg4[nt] + lb4[nt];
        }
    }
    // consume batch 3; stash rowgroup sum in Abuf (dead since the barriers)
    ps += (pv[0] + pv[1]) + (pv[2] + pv[3]);
    {
        float* AbufF = (float*)Abuf;
        ((v4f*)AbufF)[rg * 128 + col4] = ps;            // AbufF[rg][512 floats]
    }

#pragma unroll
    for (int nt = 0; nt < 4; nt++) {
        col[nt] += __shfl_xor(col[nt], 16);
        col[nt] += __shfl_xor(col[nt], 32);
    }
    if (lane < 16) {
#pragma unroll
        for (int nt = 0; nt < 4; nt++) ColS[wv * 64 + nt * 16 + c] = col[nt];
    }
    __syncthreads();

    // ---- combined partial row: LN column sums + prev column sums ----
    {
        const float* AbufF = (const float*)Abuf;
        float prevc = (AbufF[t] + AbufF[512 + t]) +
                      (AbufF[1024 + t] + AbufF[1536 + t]);
        partialG[(size_t)gix * 512 + t] = ColS[t] + prevc;
    }
}

// ---- head: fused partial-reduce + 3-layer MLP. Each block redundantly sums
// the 64 partial rows (L2-hot, 128KB/block), then h1,h2 redundant + a
// 40-output slice of layer 3 (wave-per-output). ------------------------------
__global__ __launch_bounds__(256)
void head_kernel(const float* __restrict__ partialG,
                 const float* __restrict__ W1, const float* __restrict__ b1,
                 const float* __restrict__ W2, const float* __restrict__ b2,
                 const float* __restrict__ W3, const float* __restrict__ b3,
                 float* __restrict__ out) {
    __shared__ __align__(16) float P[512];
    __shared__ __align__(16) float H1[256];
    __shared__ __align__(16) float H2[256];
    const int t = threadIdx.x, wv = t >> 6, lane = t & 63;
    const int b = blockIdx.x / 25;
    const int slice = blockIdx.x % 25;                 // 25 slices x 40 outputs

    // fused reduction: cols t and t+256 over 64 combined partial rows
    {
        const float* pg = partialG + (size_t)b * 64 * 512;
        float a0 = 0.f, a1 = 0.f, a2 = 0.f, a3 = 0.f;
#pragma unroll 4
        for (int i = 0; i < 64; i += 2) {
            a0 += pg[i * 512 + t];
            a1 += pg[(i + 1) * 512 + t];
            a2 += pg[i * 512 + t + 256];
            a3 += pg[(i + 1) * 512 + t + 256];
        }
        P[t] = (a0 + a1) * (1.f / 4096.f);
        P[t + 256] = (a2 + a3) * (1.f / 4096.f);
    }
    __syncthreads();

    // h1[t] = relu(W1[t,:] . P + b1[t])   (128 independent float4 loads)
    {
        const float4* wr = (const float4*)(W1 + t * C_);
        float s = 0.f;
#pragma unroll 8
        for (int k = 0; k < 128; k++) {
            float4 w = wr[k];
            float4 p = ((const float4*)P)[k];
            s += w.x * p.x + w.y * p.y + w.z * p.z + w.w * p.w;
        }
        H1[t] = fmaxf(s + b1[t], 0.f);
    }
    __syncthreads();

    // h2[t] = relu(W2[t,:] . H1 + b2[t])
    {
        const float4* wr = (const float4*)(W2 + t * H_);
        float s = 0.f;
#pragma unroll 8
        for (int k = 0; k < 64; k++) {
            float4 w = wr[k];
            float4 p = ((const float4*)H1)[k];
            s += w.x * p.x + w.y * p.y + w.z * p.z + w.w * p.w;
        }
        H2[t] = fmaxf(s + b2[t], 0.f);
    }
    __syncthreads();

    // layer 3: this block's 40 outputs, wave-per-output (coalesced W3 row)
#pragma unroll
    for (int jj = 0; jj < 10; jj++) {
        const int o = slice * 40 + jj * 4 + wv;
        float4 w = ((const float4*)(W3 + o * H_))[lane];
        float4 p = ((const float4*)H2)[lane];
        float s = w.x * p.x + w.y * p.y + w.z * p.z + w.w * p.w;
#pragma unroll
        for (int d = 1; d < 64; d <<= 1) s += __shfl_xor(s, d);
        if (lane == 0) out[b * NC_ + o] = s + b3[o];
    }
}

extern "C" void kernel_launch(void* const* d_in, const int* in_sizes, int n_in,
                              void* d_out, int out_size, void* d_ws, size_t ws_size,
                              hipStream_t stream) {
    const float* feat  = (const float*)d_in[0];
    const float* prev  = (const float*)d_in[1];
    // d_in[2] = pos_org, d_in[3] = pos_shuffled — UNUSED: the gather is a row
    // permutation and the only consumer (token mean) is permutation-invariant.
    const float* projW = (const float*)d_in[4];
    const float* pb    = (const float*)d_in[5];
    const float* lg    = (const float*)d_in[6];
    const float* lb    = (const float*)d_in[7];
    const float* W1    = (const float*)d_in[8];
    const float* b1    = (const float*)d_in[9];
    const float* W2    = (const float*)d_in[10];
    const float* b2    = (const float*)d_in[11];
    const float* W3    = (const float*)d_in[12];
    const float* b3    = (const float*)d_in[13];
    float* out = (float*)d_out;

    char* ws = (char*)d_ws;
    ushort_t* Wfrag  = (ushort_t*)ws;                    // 524288 B (exact)
    float* partialG  = (float*)(ws + 524288);            // 512*512*4 = 1048576 B

    prep_kernel<<<128, 256, 0, stream>>>(projW, Wfrag);
    gemm_ln_pool<<<512, 512, 0, stream>>>(feat, prev, Wfrag,
                                          pb, lg, lb, partialG);
    head_kernel<<<200, 256, 0, stream>>>(partialG,
                                         W1, b1, W2, b2, W3, b3, out);
}

// Round 14
// 215.808 us; speedup vs baseline: 1.0168x; 1.0168x over previous
//
#include <hip/hip_runtime.h>
#include <stdint.h>

#define B_ 8
#define N_ 4096
#define C_ 512
#define H_ 256
#define NC_ 1000

typedef float v4f __attribute__((ext_vector_type(4)));
typedef short v8s __attribute__((ext_vector_type(8)));
typedef unsigned short ushort_t;

__device__ __forceinline__ uint32_t f2bf1(float f) {
    uint32_t u = __float_as_uint(f);
    return (u + 0x7FFFu + ((u >> 16) & 1u)) >> 16;
}
__device__ __forceinline__ uint32_t pk2(float lo, float hi) {
#if __has_builtin(__builtin_amdgcn_cvt_pk_bf16_f32)
    auto r = __builtin_amdgcn_cvt_pk_bf16_f32(lo, hi);   // v_cvt_pk_bf16_f32
    return __builtin_bit_cast(uint32_t, r);
#else
    return f2bf1(lo) | (f2bf1(hi) << 16);
#endif
}

// ---- prep: proj_W -> bf16 B-fragment order only (gather is dead code: the
// permutation feeds a permutation-invariant token mean). --------------------
// Wfrag (uint4 units): slot[(ntile*16 + kb)*64 + q*16 + c] holds
// bf16(W[ntile*16+c][kb*32 + q*8 + j]), j=0..7.  (exact 524288 B)
__global__ void prep_kernel(const float* __restrict__ W, ushort_t* __restrict__ Wfrag) {
    int i = blockIdx.x * 256 + threadIdx.x;            // 0..32767 = d*64 + kb*4 + q
    int d = i >> 6, kb = (i >> 2) & 15, q = i & 3;
    const float4* src = (const float4*)(W + d * C_ + kb * 32 + q * 8);
    float4 v0 = src[0], v1 = src[1];
    uint4 pk;
    pk.x = pk2(v0.x, v0.y); pk.y = pk2(v0.z, v0.w);
    pk.z = pk2(v1.x, v1.y); pk.w = pk2(v1.z, v1.w);
    ((uint4*)Wfrag)[((d >> 4) * 16 + kb) * 64 + q * 16 + (d & 15)] = pk;
}

// ---- fused GEMM+bias+LN+col-pool + prev-pool, 512 blocks = EXACTLY 2/CU ----
// SESSION-BEST FORM (R12: total 214.7us, gemm ~45us). Structure findings:
//  * 512 blocks = one clean residency round (768-block 1.5-round tail cost
//    ~1.5x makespan, R11->R12 = -6us).
//  * prev pooled in the EPILOGUE (two 8-deep v4f batches hidden under the
//    stats/normalize passes) — NOT phase 1 (R1: poisons vm queue pre-K-loop)
//    and NOT a separate role (R7: needs the 768 grid).
//  * zero global atomics (R5: device atomics on 256 cache lines = 68us) and
//    zero device fences (R10: threadfence = L2 writeback on non-coherent
//    XCDs, 7x). Partials to workspace; head reduces.
//  * R13 tried 4-deep prev batches to cut the known ~4.7MB spill: longer
//    live ranges spilled MORE (18MB, +3.6us). Keep the 8-deep form.
__global__ __launch_bounds__(512, 4)
void gemm_ln_pool(const float* __restrict__ feat, const float* __restrict__ prev,
                  const ushort_t* __restrict__ Wfrag,
                  const float* __restrict__ pb, const float* __restrict__ lg,
                  const float* __restrict__ lb,
                  float* __restrict__ partialG) {    // [512][512]
    __shared__ v8s Abuf[4096];          // 64KB A-tile; reused as prev scratch
    __shared__ float RowS[64], RowQ[64], ColS[512];

    const int gix = blockIdx.x;                         // 0..511
    const int t = threadIdx.x;
    const int b = gix >> 6;
    const int row0 = (gix & 63) << 6;
    const int wv = t >> 6, lane = t & 63, c = lane & 15, q = lane >> 4;

    if (t < 64) { RowS[t] = 0.f; RowQ[t] = 0.f; }

    // ---- phase 1: stage A tile (sequential rows, fp32->bf16), nt loads ----
    const int arow = t >> 3;                           // 0..63
    const int acol8 = t & 7;
    const v4f* asrc = (const v4f*)(feat + ((size_t)(b * N_ + row0 + arow) * C_));
#pragma unroll 4
    for (int s = 0; s < 8; s++) {
        const int chunk = s * 8 + acol8;               // logical 16B-chunk 0..63
        v4f f0 = __builtin_nontemporal_load(asrc + chunk * 2);
        v4f f1 = __builtin_nontemporal_load(asrc + chunk * 2 + 1);
        uint4 pk;
        pk.x = pk2(f0.x, f0.y); pk.y = pk2(f0.z, f0.w);
        pk.z = pk2(f1.x, f1.y); pk.w = pk2(f1.z, f1.w);
        ((uint4*)Abuf)[arow * 64 + (chunk ^ (arow & 7))] = pk;
    }

    // B fragment bases: wave wv owns cols [64*wv, 64*wv+64), ntile = wv*4+nt
    const ushort_t* fb[4];
#pragma unroll
    for (int nt = 0; nt < 4; nt++)
        fb[nt] = Wfrag + (wv * 4 + nt) * 8192 + lane * 8;

    v4f acc[4][4];
    const v4f vzero = {0.f, 0.f, 0.f, 0.f};
#pragma unroll
    for (int mt = 0; mt < 4; mt++)
#pragma unroll
        for (int nt = 0; nt < 4; nt++) acc[mt][nt] = vzero;

    __syncthreads();

    // ---- phase 2: barrier-free K loop, only L2/L3-hit B loads in vm queue
#pragma unroll 2
    for (int kb = 0; kb < 16; kb++) {
        v8s af[4], bf[4];
#pragma unroll
        for (int nt = 0; nt < 4; nt++)
            bf[nt] = *((const v8s*)(fb[nt] + kb * 512));
#pragma unroll
        for (int mt = 0; mt < 4; mt++)
            af[mt] = Abuf[(mt * 16 + c) * 64 + ((kb * 4 + q) ^ (c & 7))];
#pragma unroll
        for (int mt = 0; mt < 4; mt++)
#pragma unroll
            for (int nt = 0; nt < 4; nt++)
                acc[mt][nt] = __builtin_amdgcn_mfma_f32_16x16x32_bf16(
                    af[mt], bf[nt], acc[mt][nt], 0, 0, 0);
    }

    // ---- prev batch 0: issue 8 v4f loads; latency hides under the bias/stats
    // VALU pass below (thread t: float4-col t&127, rowgroup t>>7 of 16 rows)
    const int col4 = t & 127, rg = t >> 7;
    const v4f* psrc =
        (const v4f*)(prev + (size_t)(b * N_ + row0 + rg * 16) * C_) + col4;
    v4f pv[8];
#pragma unroll
    for (int r = 0; r < 8; r++)
        pv[r] = __builtin_nontemporal_load(psrc + r * 128);

    // ---- epilogue pass 1: bias, LN row stats (LDS atomics on-CU) ----
    float pb4[4], lg4[4], lb4[4];
#pragma unroll
    for (int nt = 0; nt < 4; nt++) {
        int n = wv * 64 + nt * 16 + c;
        pb4[nt] = pb[n]; lg4[nt] = lg[n]; lb4[nt] = lb[n];
    }
#pragma unroll
    for (int mt = 0; mt < 4; mt++) {
#pragma unroll
        for (int reg = 0; reg < 4; reg++) {
            float s1 = 0.f, s2 = 0.f;
#pragma unroll
            for (int nt = 0; nt < 4; nt++) {
                float v = acc[mt][nt][reg] + pb4[nt];
                acc[mt][nt][reg] = v;
                s1 += v; s2 += v * v;
            }
#pragma unroll
            for (int d = 1; d < 16; d <<= 1) {
                s1 += __shfl_xor(s1, d);
                s2 += __shfl_xor(s2, d);
            }
            if (c == 0) {
                int r = mt * 16 + q * 4 + reg;
                atomicAdd(&RowS[r], s1);
                atomicAdd(&RowQ[r], s2);
            }
        }
    }
    __syncthreads();
    if (t < 64) {
        float mu = RowS[t] * (1.f / C_);
        float var = RowQ[t] * (1.f / C_) - mu * mu;
        RowS[t] = mu;
        RowQ[t] = rsqrtf(var + 1e-5f);
    }
    // consume prev batch 0; issue batch 1 (hides under stats barrier + col pass)
    v4f ps0 = (pv[0] + pv[1]) + (pv[2] + pv[3]);
    v4f ps1 = (pv[4] + pv[5]) + (pv[6] + pv[7]);
#pragma unroll
    for (int r = 0; r < 8; r++)
        pv[r] = __builtin_nontemporal_load(psrc + (8 + r) * 128);
    __syncthreads();

    // consume batch 1; stash rowgroup sum in Abuf (dead since K-loop + barrier)
    {
        v4f ps = (ps0 + ps1) +
                 ((pv[0] + pv[1]) + (pv[2] + pv[3])) +
                 ((pv[4] + pv[5]) + (pv[6] + pv[7]));
        float* AbufF = (float*)Abuf;
        ((v4f*)AbufF)[rg * 128 + col4] = ps;            // AbufF[rg][512 floats]
    }

    // ---- epilogue pass 2: normalize + column pool ----
    float col[4] = {0.f, 0.f, 0.f, 0.f};
#pragma unroll
    for (int mt = 0; mt < 4; mt++) {
#pragma unroll
        for (int reg = 0; reg < 4; reg++) {
            int r = mt * 16 + q * 4 + reg;
            float mu = RowS[r], rs = RowQ[r];
#pragma unroll
            for (int nt = 0; nt < 4; nt++)
                col[nt] += (acc[mt][nt][reg] - mu) * rs * lg4[nt] + lb4[nt];
        }
    }
#pragma unroll
    for (int nt = 0; nt < 4; nt++) {
        col[nt] += __shfl_xor(col[nt], 16);
        col[nt] += __shfl_xor(col[nt], 32);
    }
    if (lane < 16) {
#pragma unroll
        for (int nt = 0; nt < 4; nt++) ColS[wv * 64 + nt * 16 + c] = col[nt];
    }
    __syncthreads();

    // ---- combined partial row: LN column sums + prev column sums ----
    {
        const float* AbufF = (const float*)Abuf;
        float prevc = (AbufF[t] + AbufF[512 + t]) +
                      (AbufF[1024 + t] + AbufF[1536 + t]);
        partialG[(size_t)gix * 512 + t] = ColS[t] + prevc;
    }
}

// ---- head: fused partial-reduce + 3-layer MLP. Each block redundantly sums
// the 64 partial rows (L2-hot, 128KB/block), then h1,h2 redundant + a
// 40-output slice of layer 3 (wave-per-output). ------------------------------
__global__ __launch_bounds__(256)
void head_kernel(const float* __restrict__ partialG,
                 const float* __restrict__ W1, const float* __restrict__ b1,
                 const float* __restrict__ W2, const float* __restrict__ b2,
                 const float* __restrict__ W3, const float* __restrict__ b3,
                 float* __restrict__ out) {
    __shared__ __align__(16) float P[512];
    __shared__ __align__(16) float H1[256];
    __shared__ __align__(16) float H2[256];
    const int t = threadIdx.x, wv = t >> 6, lane = t & 63;
    const int b = blockIdx.x / 25;
    const int slice = blockIdx.x % 25;                 // 25 slices x 40 outputs

    // fused reduction: cols t and t+256 over 64 combined partial rows
    {
        const float* pg = partialG + (size_t)b * 64 * 512;
        float a0 = 0.f, a1 = 0.f, a2 = 0.f, a3 = 0.f;
#pragma unroll 4
        for (int i = 0; i < 64; i += 2) {
            a0 += pg[i * 512 + t];
            a1 += pg[(i + 1) * 512 + t];
            a2 += pg[i * 512 + t + 256];
            a3 += pg[(i + 1) * 512 + t + 256];
        }
        P[t] = (a0 + a1) * (1.f / 4096.f);
        P[t + 256] = (a2 + a3) * (1.f / 4096.f);
    }
    __syncthreads();

    // h1[t] = relu(W1[t,:] . P + b1[t])   (128 independent float4 loads)
    {
        const float4* wr = (const float4*)(W1 + t * C_);
        float s = 0.f;
#pragma unroll 8
        for (int k = 0; k < 128; k++) {
            float4 w = wr[k];
            float4 p = ((const float4*)P)[k];
            s += w.x * p.x + w.y * p.y + w.z * p.z + w.w * p.w;
        }
        H1[t] = fmaxf(s + b1[t], 0.f);
    }
    __syncthreads();

    // h2[t] = relu(W2[t,:] . H1 + b2[t])
    {
        const float4* wr = (const float4*)(W2 + t * H_);
        float s = 0.f;
#pragma unroll 8
        for (int k = 0; k < 64; k++) {
            float4 w = wr[k];
            float4 p = ((const float4*)H1)[k];
            s += w.x * p.x + w.y * p.y + w.z * p.z + w.w * p.w;
        }
        H2[t] = fmaxf(s + b2[t], 0.f);
    }
    __syncthreads();

    // layer 3: this block's 40 outputs, wave-per-output (coalesced W3 row)
#pragma unroll
    for (int jj = 0; jj < 10; jj++) {
        const int o = slice * 40 + jj * 4 + wv;
        float4 w = ((const float4*)(W3 + o * H_))[lane];
        float4 p = ((const float4*)H2)[lane];
        float s = w.x * p.x + w.y * p.y + w.z * p.z + w.w * p.w;
#pragma unroll
        for (int d = 1; d < 64; d <<= 1) s += __shfl_xor(s, d);
        if (lane == 0) out[b * NC_ + o] = s + b3[o];
    }
}

extern "C" void kernel_launch(void* const* d_in, const int* in_sizes, int n_in,
                              void* d_out, int out_size, void* d_ws, size_t ws_size,
                              hipStream_t stream) {
    const float* feat  = (const float*)d_in[0];
    const float* prev  = (const float*)d_in[1];
    // d_in[2] = pos_org, d_in[3] = pos_shuffled — UNUSED: the gather is a row
    // permutation and the only consumer (token mean) is permutation-invariant.
    const float* projW = (const float*)d_in[4];
    const float* pb    = (const float*)d_in[5];
    const float* lg    = (const float*)d_in[6];
    const float* lb    = (const float*)d_in[7];
    const float* W1    = (const float*)d_in[8];
    const float* b1    = (const float*)d_in[9];
    const float* W2    = (const float*)d_in[10];
    const float* b2    = (const float*)d_in[11];
    const float* W3    = (const float*)d_in[12];
    const float* b3    = (const float*)d_in[13];
    float* out = (float*)d_out;

    char* ws = (char*)d_ws;
    ushort_t* Wfrag  = (ushort_t*)ws;                    // 524288 B (exact)
    float* partialG  = (float*)(ws + 524288);            // 512*512*4 = 1048576 B

    prep_kernel<<<128, 256, 0, stream>>>(projW, Wfrag);
    gemm_ln_pool<<<512, 512, 0, stream>>>(feat, prev, Wfrag,
                                          pb, lg, lb, partialG);
    head_kernel<<<200, 256, 0, stream>>>(partialG,
                                         W1, b1, W2, b2, W3, b3, out);
}